// Round 1
// baseline (1191.773 us; speedup 1.0000x reference)
//
#include <hip/hip_runtime.h>
#include <math.h>

#define HDIM 128
#define TN 8

// ---------------- CSR build ----------------

__global__ void zero_deg(int* __restrict__ deg, int n) {
    int i = blockIdx.x * blockDim.x + threadIdx.x;
    if (i < n) deg[i] = 0;
}

__global__ void hist_kernel(const int* __restrict__ ei, int* __restrict__ deg, int E_) {
    int e = blockIdx.x * blockDim.x + threadIdx.x;
    if (e < E_) atomicAdd(&deg[ei[E_ + e]], 1);
}

__global__ void scan1(const int* __restrict__ deg, int* __restrict__ off1,
                      int* __restrict__ bsum, int n) {
    __shared__ int sd[1024];
    int tid = threadIdx.x;
    int i = blockIdx.x * 1024 + tid;
    sd[tid] = (i < n) ? deg[i] : 0;
    __syncthreads();
    for (int ofs = 1; ofs < 1024; ofs <<= 1) {
        int add = (tid >= ofs) ? sd[tid - ofs] : 0;
        __syncthreads();
        sd[tid] += add;
        __syncthreads();
    }
    if (i < n) off1[i] = sd[tid];
    if (tid == 1023) bsum[blockIdx.x] = sd[1023];
}

__global__ void scan2(int* __restrict__ bsum, int nb) {
    __shared__ int sd[1024];
    int tid = threadIdx.x;
    sd[tid] = (tid < nb) ? bsum[tid] : 0;
    __syncthreads();
    for (int ofs = 1; ofs < 1024; ofs <<= 1) {
        int add = (tid >= ofs) ? sd[tid - ofs] : 0;
        __syncthreads();
        sd[tid] += add;
        __syncthreads();
    }
    if (tid < nb) bsum[tid] = sd[tid];
}

__global__ void scan3(int* __restrict__ off1, const int* __restrict__ bsum, int n) {
    int i = blockIdx.x * 1024 + threadIdx.x;
    if (blockIdx.x > 0 && i < n) off1[i] += bsum[blockIdx.x - 1];
}

// set off[0]=0 and copy cursor[i] = off[i]
__global__ void prep_kernel(int* __restrict__ off, int* __restrict__ cursor, int n) {
    int i = blockIdx.x * blockDim.x + threadIdx.x;
    if (i < n) cursor[i] = (i == 0) ? 0 : off[i];
    if (i == 0) off[0] = 0;
}

__global__ void scatter_kernel(const int* __restrict__ ei, int* __restrict__ cursor,
                               int* __restrict__ srcs, int E_) {
    int e = blockIdx.x * blockDim.x + threadIdx.x;
    if (e < E_) {
        int d = ei[E_ + e];
        int pos = atomicAdd(&cursor[d], 1);
        srcs[pos] = ei[e];
    }
}

// ---------------- weight transpose (W[j][k] -> WT[k][j]) ----------------

__global__ void transpose128(const float* __restrict__ W, float* __restrict__ WT) {
    int id = blockIdx.x * blockDim.x + threadIdx.x;  // HDIM*HDIM threads
    int k = id >> 7, j = id & 127;
    WT[k * HDIM + j] = W[j * HDIM + k];
}

// ---------------- fused SAGE layer (agg + 2 linears + elu [+residual]) ----------------

__global__ __launch_bounds__(HDIM) void sage_mid(
    const float* __restrict__ in_h, float* __restrict__ out_h,
    const int* __restrict__ off, const int* __restrict__ srcs,
    const float* __restrict__ WlT, const float* __restrict__ bl,
    const float* __restrict__ WrT, int residual, int n_nodes)
{
    __shared__ float sm[TN][HDIM];
    __shared__ float sh[TN][HDIM];
    int t = threadIdx.x;
    int base = blockIdx.x * TN;

    for (int n = 0; n < TN; ++n) {
        int node = base + n;
        if (node >= n_nodes) { sm[n][t] = 0.f; sh[n][t] = 0.f; continue; }
        sh[n][t] = in_h[node * HDIM + t];
        int e0 = off[node], e1 = off[node + 1];
        float m = -INFINITY;
        for (int e = e0; e < e1; ++e) {
            int s = srcs[e];
            m = fmaxf(m, in_h[s * HDIM + t]);
        }
        sm[n][t] = (e1 > e0) ? m : 0.f;
    }
    __syncthreads();

    float acc[TN];
#pragma unroll
    for (int n = 0; n < TN; ++n) acc[n] = 0.f;

    for (int k4 = 0; k4 < HDIM; k4 += 4) {
        float4 wl, wr;
        wl.x = WlT[(k4 + 0) * HDIM + t]; wl.y = WlT[(k4 + 1) * HDIM + t];
        wl.z = WlT[(k4 + 2) * HDIM + t]; wl.w = WlT[(k4 + 3) * HDIM + t];
        wr.x = WrT[(k4 + 0) * HDIM + t]; wr.y = WrT[(k4 + 1) * HDIM + t];
        wr.z = WrT[(k4 + 2) * HDIM + t]; wr.w = WrT[(k4 + 3) * HDIM + t];
#pragma unroll
        for (int n = 0; n < TN; ++n) {
            float4 a = *(const float4*)&sm[n][k4];
            float4 b = *(const float4*)&sh[n][k4];
            acc[n] += a.x * wl.x + a.y * wl.y + a.z * wl.z + a.w * wl.w
                    + b.x * wr.x + b.y * wr.y + b.z * wr.z + b.w * wr.w;
        }
    }

    float blv = bl[t];
    for (int n = 0; n < TN; ++n) {
        int node = base + n;
        if (node >= n_nodes) break;
        float v = acc[n] + blv;
        v = (v > 0.f) ? v : (expf(v) - 1.f);
        if (residual) v += sh[n][t];
        out_h[node * HDIM + t] = v;
    }
}

// layer 3 fused with readout: out = sigmoid(h3 . Wo + bo)
__global__ __launch_bounds__(HDIM) void sage_last(
    const float* __restrict__ in_h, float* __restrict__ out,
    const int* __restrict__ off, const int* __restrict__ srcs,
    const float* __restrict__ WlT, const float* __restrict__ bl,
    const float* __restrict__ WrT,
    const float* __restrict__ Wo, const float* __restrict__ bo, int n_nodes)
{
    __shared__ float sm[TN][HDIM];
    __shared__ float sh[TN][HDIM];
    __shared__ float sv[TN][HDIM];
    int t = threadIdx.x;
    int base = blockIdx.x * TN;

    for (int n = 0; n < TN; ++n) {
        int node = base + n;
        if (node >= n_nodes) { sm[n][t] = 0.f; sh[n][t] = 0.f; continue; }
        sh[n][t] = in_h[node * HDIM + t];
        int e0 = off[node], e1 = off[node + 1];
        float m = -INFINITY;
        for (int e = e0; e < e1; ++e) {
            int s = srcs[e];
            m = fmaxf(m, in_h[s * HDIM + t]);
        }
        sm[n][t] = (e1 > e0) ? m : 0.f;
    }
    __syncthreads();

    float acc[TN];
#pragma unroll
    for (int n = 0; n < TN; ++n) acc[n] = 0.f;

    for (int k4 = 0; k4 < HDIM; k4 += 4) {
        float4 wl, wr;
        wl.x = WlT[(k4 + 0) * HDIM + t]; wl.y = WlT[(k4 + 1) * HDIM + t];
        wl.z = WlT[(k4 + 2) * HDIM + t]; wl.w = WlT[(k4 + 3) * HDIM + t];
        wr.x = WrT[(k4 + 0) * HDIM + t]; wr.y = WrT[(k4 + 1) * HDIM + t];
        wr.z = WrT[(k4 + 2) * HDIM + t]; wr.w = WrT[(k4 + 3) * HDIM + t];
#pragma unroll
        for (int n = 0; n < TN; ++n) {
            float4 a = *(const float4*)&sm[n][k4];
            float4 b = *(const float4*)&sh[n][k4];
            acc[n] += a.x * wl.x + a.y * wl.y + a.z * wl.z + a.w * wl.w
                    + b.x * wr.x + b.y * wr.y + b.z * wr.z + b.w * wr.w;
        }
    }

    float blv = bl[t];
    for (int n = 0; n < TN; ++n) {
        float v = acc[n] + blv;
        v = (v > 0.f) ? v : (expf(v) - 1.f);
        v += sh[n][t];  // residual (layer 3 always has it)
        sv[n][t] = v;
    }
    __syncthreads();

    // readout: 16 lanes per node
    int n = t >> 4, l = t & 15;
    float s = 0.f;
    for (int j = l; j < HDIM; j += 16) s += sv[n][j] * Wo[j];
    for (int o = 8; o; o >>= 1) s += __shfl_down(s, o, 16);
    if (l == 0) {
        int node = base + n;
        if (node < n_nodes) out[node] = 1.f / (1.f + expf(-(s + bo[0])));
    }
}

// ---------------- launch ----------------

extern "C" void kernel_launch(void* const* d_in, const int* in_sizes, int n_in,
                              void* d_out, int out_size, void* d_ws, size_t ws_size,
                              hipStream_t stream) {
    const float* x   = (const float*)d_in[0];
    const int*   ei  = (const int*)d_in[1];
    const float* W1l = (const float*)d_in[2];
    const float* b1  = (const float*)d_in[3];
    const float* W1r = (const float*)d_in[4];
    const float* W2l = (const float*)d_in[5];
    const float* b2  = (const float*)d_in[6];
    const float* W2r = (const float*)d_in[7];
    const float* W3l = (const float*)d_in[8];
    const float* b3  = (const float*)d_in[9];
    const float* W3r = (const float*)d_in[10];
    const float* Wo  = (const float*)d_in[11];
    const float* bo  = (const float*)d_in[12];
    float* out = (float*)d_out;

    const int N_ = in_sizes[0] / HDIM;
    const int E_ = in_sizes[1] / 2;

    // workspace carve-up (256B aligned)
    size_t o = 0;
    auto carve = [&](size_t bytes) { size_t r = o; o = (o + bytes + 255) & ~255ULL; return r; };
    char* ws = (char*)d_ws;
    int* deg_cursor = (int*)(ws + carve((size_t)N_ * 4));         // deg, then reused as cursor
    int* off        = (int*)(ws + carve((size_t)(N_ + 1) * 4));
    int* bsum       = (int*)(ws + carve(1024 * 4));
    int* srcs       = (int*)(ws + carve((size_t)E_ * 4));
    float* WT       = (float*)(ws + carve((size_t)6 * HDIM * HDIM * 4));
    float* B0       = (float*)(ws + carve((size_t)N_ * HDIM * 4));
    float* B1       = (float*)(ws + carve((size_t)N_ * HDIM * 4));
    (void)ws_size; (void)n_in; (void)out_size;

    float* W1lT = WT + 0 * HDIM * HDIM;
    float* W1rT = WT + 1 * HDIM * HDIM;
    float* W2lT = WT + 2 * HDIM * HDIM;
    float* W2rT = WT + 3 * HDIM * HDIM;
    float* W3lT = WT + 4 * HDIM * HDIM;
    float* W3rT = WT + 5 * HDIM * HDIM;

    const int nbN  = (N_ + 255) / 256;
    const int nbE  = (E_ + 255) / 256;
    const int nbS  = (N_ + 1023) / 1024;   // scan blocks (98)

    // CSR build
    zero_deg<<<nbN, 256, 0, stream>>>(deg_cursor, N_);
    hist_kernel<<<nbE, 256, 0, stream>>>(ei, deg_cursor, E_);
    scan1<<<nbS, 1024, 0, stream>>>(deg_cursor, off + 1, bsum, N_);
    scan2<<<1, 1024, 0, stream>>>(bsum, nbS);
    scan3<<<nbS, 1024, 0, stream>>>(off + 1, bsum, N_);
    prep_kernel<<<nbN, 256, 0, stream>>>(off, deg_cursor, N_);
    scatter_kernel<<<nbE, 256, 0, stream>>>(ei, deg_cursor, srcs, E_);

    // transpose weights
    const int nbT = (HDIM * HDIM + 255) / 256;
    transpose128<<<nbT, 256, 0, stream>>>(W1l, W1lT);
    transpose128<<<nbT, 256, 0, stream>>>(W1r, W1rT);
    transpose128<<<nbT, 256, 0, stream>>>(W2l, W2lT);
    transpose128<<<nbT, 256, 0, stream>>>(W2r, W2rT);
    transpose128<<<nbT, 256, 0, stream>>>(W3l, W3lT);
    transpose128<<<nbT, 256, 0, stream>>>(W3r, W3rT);

    // layers
    const int nbL = (N_ + TN - 1) / TN;
    sage_mid<<<nbL, HDIM, 0, stream>>>(x,  B0, off, srcs, W1lT, b1, W1rT, 0, N_);
    sage_mid<<<nbL, HDIM, 0, stream>>>(B0, B1, off, srcs, W2lT, b2, W2rT, 1, N_);
    sage_last<<<nbL, HDIM, 0, stream>>>(B1, out, off, srcs, W3lT, b3, W3rT, Wo, bo, N_);
}